// Round 5
// baseline (201.764 us; speedup 1.0000x reference)
//
#include <hip/hip_runtime.h>
#include <hip/hip_bf16.h>

// TFData2VecVisionSelfAttention: B=16,S=577,D=768,H=12,HEAD=64. fp32 in/out.
// R14: attn restructured 8 waves x 16q -> 4 waves x 32q (256 threads). Each
// wave computes 2 m-fragments sharing every kf/vf LDS read -> per-block
// ds_read_b128 traffic halves (attn was LDS-pipe-bound: 8 waves all reading
// the same Ks/VTs; ~43K LDS cycles demanded per 35K-cycle block at 3
// blocks/CU). MFMA count unchanged, per-wave ILP doubles. qkv_gemm (R11
// single-round 256x384/BK=32 triple-buffer), prep, prep2 byte-identical.
// Workspace (bytes, phase-overlapped), total 67.1 MB:
//   qkv   [0, 42541056)                      3 x 9232x768 bf16 m-major (q,k,v)
//   WT    [42541056, 46080000)   phase 1     3x768x768 bf16
//   Xb    [46080000, 60260352)   phase 1     9232x768 bf16
//   vT    [42541056, 58269696)   phase 2     192x64x640 bf16 (over WT+Xb)
//   biasm [58269696, 67132416)   phase 2     12x577x640 bf16 (over Xb tail)

typedef __attribute__((ext_vector_type(8))) short bf16x8;   // 8 x bf16 (4 VGPRs)
typedef __attribute__((ext_vector_type(4))) float f32x4;
typedef unsigned short u16;

#define SEQ 577
#define MTOT 9232            // 16*577
#define QKV_STRIDE 7090176   // 9232*768 elements per q/k/v buffer
#define VT_PITCH 640         // keys per vT row (pad 577..639 zero-filled)
#define B_PITCH 640          // bias row pitch (pad zero-filled)

// fp32 -> bf16 round-to-nearest-even
static __device__ __forceinline__ u16 f2bf(float x) {
  unsigned int u = __float_as_uint(x);
  u = (u + 0x7FFFu + ((u >> 16) & 1u)) >> 16;
  return (u16)u;
}
static __device__ __forceinline__ float bf2f(u16 v) {
  return __uint_as_float(((unsigned int)v) << 16);
}

// async global->LDS, 16B per lane; LDS dest = wave-uniform base + lane*16
static __device__ __forceinline__ void gload_lds16(const void* g, void* l) {
  __builtin_amdgcn_global_load_lds(
      (const __attribute__((address_space(1))) unsigned int*)g,
      (__attribute__((address_space(3))) unsigned int*)l, 16, 0, 0);
}

// ---------------- prep: transpose_w (blocks 0..1727) + cvt_x (1728..5189) ----------------
__global__ __launch_bounds__(256) void prep(
    const float* __restrict__ Wq, const float* __restrict__ Wk,
    const float* __restrict__ Wv, const float* __restrict__ X,
    u16* __restrict__ WT, u16* __restrict__ Xb) {
  const int bid = blockIdx.x;
  if (bid < 1728) {
    __shared__ float t[32][33];
    const int z = bid / 576;
    const int rem = bid - z * 576;
    const int kx = rem % 24, ny = rem / 24;
    const float* W = (z == 0) ? Wq : (z == 1) ? Wk : Wv;
    int x = threadIdx.x & 31;
    int y = threadIdx.x >> 5;  // 0..7
    int k0 = kx * 32;
    int n0 = ny * 32;
#pragma unroll
    for (int i = 0; i < 4; ++i)
      t[y + i * 8][x] = W[(size_t)(k0 + y + i * 8) * 768 + n0 + x];
    __syncthreads();
    u16* o = WT + (size_t)z * 589824;
#pragma unroll
    for (int i = 0; i < 4; ++i)
      o[(size_t)(n0 + y + i * 8) * 768 + k0 + x] = f2bf(t[x][y + i * 8]);
  } else {
    size_t i = ((size_t)(bid - 1728) * 256 + threadIdx.x) * 8;
    if (i >= (size_t)MTOT * 768) return;
    const float4* xp = (const float4*)(X + i);
    float4 a = xp[0], b = xp[1];
    u16 pk[8] = {f2bf(a.x), f2bf(a.y), f2bf(a.z), f2bf(a.w),
                 f2bf(b.x), f2bf(b.y), f2bf(b.z), f2bf(b.w)};
    *(int4*)(Xb + i) = *(const int4*)pk;
  }
}

// ---------------- prep2: transpose_v (blocks 0..959) + bias_pre (960..7883) ----------------
__global__ __launch_bounds__(256) void prep2(
    const u16* __restrict__ v,      // v buffer, [m][768]
    u16* __restrict__ vT,           // [bh][64][640]
    const float* __restrict__ table, const int* __restrict__ idx,
    u16* __restrict__ biasm) {
  const int bid = blockIdx.x;
  const int tid = threadIdx.x;
  if (bid < 960) {
    const int tile = bid % 5;   // s0 = tile*128
    const int bh = bid / 5;     // 0..191
    const int b = bh / 12, h = bh % 12;
    __shared__ u16 T[128][64];
    const int s0 = tile * 128;
    const u16* vp = v + (size_t)b * SEQ * 768 + h * 64;
#pragma unroll
    for (int it = 0; it < 4; ++it) {
      int c = tid + it * 256;          // 1024 chunks of 16B
      int r = c >> 3, ko = (c & 7) << 3;
      int gs = s0 + r;
      int4 val = make_int4(0, 0, 0, 0);
      if (gs < SEQ) val = *(const int4*)(vp + (size_t)gs * 768 + ko);
      *(int4*)&T[r][ko ^ (((r >> 3) & 7) << 3)] = val;  // swizzled store
    }
    __syncthreads();
    u16* op = vT + (size_t)bh * 64 * VT_PITCH;
#pragma unroll
    for (int it = 0; it < 4; ++it) {
      int c = tid + it * 256;          // d = c>>4, so = (c&15)*8
      int d = c >> 4, so = (c & 15) << 3;
      u16 tmp[8];
#pragma unroll
      for (int j = 0; j < 8; ++j) {
        int rr = so + j;
        tmp[j] = T[rr][d ^ (((rr >> 3) & 7) << 3)];
      }
      *(int4*)(op + (size_t)d * VT_PITCH + s0 + so) = *(const int4*)tmp;
    }
  } else {
    const int r = bid - 960;        // 0..6923
    const int q = r % 577;
    const int h = r / 577;
    for (int k = tid; k < B_PITCH; k += 256) {
      u16 vv = 0;
      if (k < SEQ) vv = f2bf(table[idx[q * SEQ + k] * 12 + h]);
      biasm[((size_t)h * SEQ + q) * B_PITCH + k] = vv;
    }
  }
}

// ---------------- fused QKV GEMM: 256x384 tile, BK=32, 8 waves, triple-buffer ----------------
// Grid: 37 M-tiles x 6 N-tiles = 222 blocks (<=256 CUs -> one round).
// N = 3 outputs x 768; nt&1 selects 384-col half, nt>>1 selects q/k/v.
// XCD pinning: bid&7 groups same-mt blocks on one XCD (shared A panel in L2).
// LDS: SAB[3][A 256x32 | B 384x32] bf16 = 120 KiB. 64B rows; chunk16 swizzle
// chunk ^= (row>>1)&3 (uniform bank spread on ds_read_b128). Stage tile t+2
// into buf (t+2)%3 spread {3,2} over the 2 phases; boundary s_waitcnt vmcnt(5).
#define G_STAGE_A(BS, KT, U)                                                   \
  gload_lds16(aptr[(U)] + (KT) * 32, &SAB[(BS)][((U) * 128 + w16) * 32])
#define G_STAGE_B(BS, KT, U)                                                   \
  gload_lds16(bptr + (size_t)(U) * 128 * 768 + (KT) * 32,                      \
              &SAB[(BS)][8192 + ((U) * 128 + w16) * 32])

__global__ __launch_bounds__(512, 2) void qkv_gemm(
    const u16* __restrict__ Xb,   // [9232][768] bf16
    const u16* __restrict__ WT,   // [3][768][768] n-major bf16
    const float* __restrict__ bq, const float* __restrict__ bv,
    u16* __restrict__ qkv) {
  const int bid = blockIdx.x;
  const int x = bid & 7;
  const int l = bid >> 3;
  const int mt = x + 8 * (l / 6);          // same-mt blocks land on one XCD
  if (mt >= 37) return;
  const int nt = l % 6;
  const int m0 = mt * 256;
  const int widx = nt >> 1;                // 0=q, 1=k, 2=v
  const int nb = (nt & 1) * 384;           // col base within [0,768)

  const int tid = threadIdx.x;
  const int lane = tid & 63;
  const int w = tid >> 6;                  // 0..7
  const int wm2 = w >> 2;                  // 0..1 (M half: 128 rows)
  const int wn = w & 3;                    // 0..3 (N quarter: 96 cols)
  const int quad = lane >> 4;
  const int l15 = lane & 15;
  const int w16 = w * 16;

  __shared__ u16 SAB[3][20480];            // per buf: A[256][32] | B[384][32]

  // ---- staging addressing: lane covers (row = w16 + lane>>2, chunk = lane&3)
  // source chunk pre-swizzled: ce = (lane&3) ^ ((lane>>3)&3)
  const int srow = w16 + (lane >> 2);
  const int ce8 = (((lane & 3) ^ ((lane >> 3) & 3))) * 8;
  const u16* aptr[2];
#pragma unroll
  for (int u = 0; u < 2; ++u) {
    int rr = m0 + u * 128 + srow;
    if (rr > MTOT - 1) rr = MTOT - 1;      // clamped rows: garbage, not stored
    aptr[u] = Xb + (size_t)rr * 768 + ce8;
  }
  const u16* bptr =
      WT + (size_t)widx * 589824 + (size_t)(nb + srow) * 768 + ce8;

  // ---- ds_read addressing (unswizzle): chunk = quad ^ ((l15>>1)&3)
  const int ca8 = (quad ^ ((l15 >> 1) & 3)) * 8;   // elems

  f32x4 acc[8][6];
#pragma unroll
  for (int i = 0; i < 8; ++i)
#pragma unroll
    for (int j = 0; j < 6; ++j) acc[i][j] = (f32x4){0.f, 0.f, 0.f, 0.f};
  bf16x8 af[4], bfr[6];

  // ---- prologue: stage tiles 0 and 1 fully (5 units each) ----
  G_STAGE_A(0, 0, 0); G_STAGE_A(0, 0, 1);
  G_STAGE_B(0, 0, 0); G_STAGE_B(0, 0, 1); G_STAGE_B(0, 0, 2);
  G_STAGE_A(1, 1, 0); G_STAGE_A(1, 1, 1);
  G_STAGE_B(1, 1, 0); G_STAGE_B(1, 1, 1); G_STAGE_B(1, 1, 2);
  asm volatile("s_waitcnt vmcnt(5)" ::: "memory");  // tile0 landed; 5 in flight
  __builtin_amdgcn_s_barrier();
  asm volatile("" ::: "memory");

  int bs = 0, bt2 = 2;
  for (int t = 0; t < 24; ++t) {
    // ---- P0: quadrant mh0 (rows wm2*128 + 0..63) x all 6 n-frags ----
#pragma unroll
    for (int i = 0; i < 4; ++i)
      af[i] = *(const bf16x8*)&SAB[bs][(wm2 * 128 + i * 16 + l15) * 32 + ca8];
#pragma unroll
    for (int j = 0; j < 6; ++j)
      bfr[j] = *(const bf16x8*)&SAB[bs][8192 + (wn * 96 + j * 16 + l15) * 32 + ca8];
    if (t <= 21) { G_STAGE_A(bt2, t + 2, 0); G_STAGE_A(bt2, t + 2, 1); G_STAGE_B(bt2, t + 2, 0); }
    asm volatile("" ::: "memory");
    __builtin_amdgcn_s_barrier();
    asm volatile("s_waitcnt lgkmcnt(0)" ::: "memory");
    __builtin_amdgcn_s_setprio(1);
#pragma unroll
    for (int j = 0; j < 6; ++j)
#pragma unroll
      for (int i = 0; i < 4; ++i)
        acc[i][j] = __builtin_amdgcn_mfma_f32_16x16x32_bf16(af[i], bfr[j],
                                                            acc[i][j], 0, 0, 0);
    __builtin_amdgcn_s_setprio(0);
    asm volatile("" ::: "memory");
    __builtin_amdgcn_s_barrier();
    asm volatile("" ::: "memory");
    // ---- P1: quadrant mh1 (rows wm2*128 + 64..127) x all 6 n-frags ----
#pragma unroll
    for (int i = 0; i < 4; ++i)
      af[i] = *(const bf16x8*)&SAB[bs][(wm2 * 128 + 64 + i * 16 + l15) * 32 + ca8];
#pragma unroll
    for (int j = 0; j < 6; ++j)
      bfr[j] = *(const bf16x8*)&SAB[bs][8192 + (wn * 96 + j * 16 + l15) * 32 + ca8];
    if (t <= 21) { G_STAGE_B(bt2, t + 2, 1); G_STAGE_B(bt2, t + 2, 2); }
    asm volatile("" ::: "memory");
    __builtin_amdgcn_s_barrier();
    asm volatile("s_waitcnt lgkmcnt(0)" ::: "memory");
    __builtin_amdgcn_s_setprio(1);
#pragma unroll
    for (int j = 0; j < 6; ++j)
#pragma unroll
      for (int i = 0; i < 4; ++i)
        acc[4 + i][j] = __builtin_amdgcn_mfma_f32_16x16x32_bf16(
            af[i], bfr[j], acc[4 + i][j], 0, 0, 0);
    __builtin_amdgcn_s_setprio(0);
    // boundary: counted wait -> tile t+1 landed; t+2's 5 units stay in flight
    if (t < 22) {
      asm volatile("s_waitcnt vmcnt(5)" ::: "memory");
    } else if (t == 22) {
      asm volatile("s_waitcnt vmcnt(0)" ::: "memory");
    }
    asm volatile("" ::: "memory");
    __builtin_amdgcn_s_barrier();
    asm volatile("" ::: "memory");
    bs = (bs == 2) ? 0 : bs + 1;
    bt2 = (bt2 == 2) ? 0 : bt2 + 1;
  }

  // ---- epilogue: scale+bias, LDS-staged (128x384 halves), full-row stores ----
  const float scale = (widx == 0) ? 0.125f : 1.0f;
  float biasv[6];
#pragma unroll
  for (int nf = 0; nf < 6; ++nf) {
    int n = nb + wn * 96 + nf * 16 + l15;
    biasv[nf] = (widx == 0) ? bq[n] * 0.125f : (widx == 2) ? bv[n] : 0.f;
  }
  u16* E = &SAB[0][0];                     // 128 x 384 u16 (96 KB)
  u16* ob = qkv + (size_t)widx * QKV_STRIDE + nb;
#pragma unroll
  for (int half = 0; half < 2; ++half) {
    if (wm2 == half) {
#pragma unroll
      for (int mf = 0; mf < 8; ++mf)
#pragma unroll
        for (int nf = 0; nf < 6; ++nf)
#pragma unroll
          for (int r = 0; r < 4; ++r) {
            int rowl = mf * 16 + quad * 4 + r;           // 0..127
            int col = wn * 96 + nf * 16 + l15;           // 0..383
            int colr = (((col >> 4) ^ quad) << 4) | (col & 15);
            E[rowl * 384 + colr] = f2bf(acc[mf][nf][r] * scale + biasv[nf]);
          }
    }
    __syncthreads();
#pragma unroll 4
    for (int it = 0; it < 12; ++it) {
      int c = it * 512 + tid;              // 128 rows x 48 chunks
      int row = c / 48;
      int ch = c - row * 48;
      int m = m0 + half * 128 + row;
      if (m < MTOT) {
        int g = (ch >> 1) ^ ((row >> 2) & 3);
        int colr = (g << 4) + (ch & 1) * 8;
        *(int4*)(ob + (size_t)m * 768 + ch * 8) = *(const int4*)&E[row * 384 + colr];
      }
    }
    __syncthreads();
  }
}

// ---------------- flash attention (no-max softmax), 256 threads / 128 q-rows ----------------
// grid (bh=192, qt=5): 192%8==0 pins all qt-blocks of one (b,h) to one XCD.
// R14: 4 waves x 32 q-rows (2 m-frags per wave). kf/vf LDS reads shared
// across both m-frags -> per-block ds_read_b128 traffic halved vs 8x16q.
__global__ __launch_bounds__(256) void attn(
    const u16* __restrict__ qk, const u16* __restrict__ vT,
    const u16* __restrict__ biasm, float* __restrict__ out) {
  const int bh = blockIdx.x;  // b*12+h
  const int qt = blockIdx.y;  // 0..4
  const int b = bh / 12, h = bh - b * 12;
  const int tid = threadIdx.x;
  const int lane = tid & 63;
  const int w = tid >> 6;     // 0..3
  const int quad = lane >> 4;
  const int l15 = lane & 15;

  const u16* qp = qk + (size_t)b * SEQ * 768 + h * 64;  // row stride 768
  const u16* kp = qp + (size_t)QKV_STRIDE;
  const u16* vtp = vT + (size_t)bh * 64 * VT_PITCH;
  const u16* bp = biasm + (size_t)h * SEQ * B_PITCH;

  __shared__ u16 Ks[64][72];     // [key][d]
  __shared__ u16 VTs[64][72];    // [d][key]
  __shared__ u16 Ps[8][16][72];  // per-(wave,mi) P tile, XOR-swizzled chunks

  const int qrow0 = qt * 128 + w * 32;   // wave owns 32 q-rows (2 m-frags)

  bf16x8 qf[2][2];
#pragma unroll
  for (int mi = 0; mi < 2; ++mi) {
    int row = qrow0 + mi * 16 + l15;
    if (row > 576) row = 576;  // clamp; clamped rows never stored
    qf[mi][0] = *(const bf16x8*)(qp + (size_t)row * 768 + quad * 8);
    qf[mi][1] = *(const bf16x8*)(qp + (size_t)row * 768 + 32 + quad * 8);
  }
  int brow[2][4];
#pragma unroll
  for (int mi = 0; mi < 2; ++mi)
#pragma unroll
    for (int r = 0; r < 4; ++r) {
      int rr = qrow0 + mi * 16 + quad * 4 + r;
      if (rr > 576) rr = 576;
      brow[mi][r] = rr;
    }

  float lacc[2][4];
#pragma unroll
  for (int mi = 0; mi < 2; ++mi)
#pragma unroll
    for (int r = 0; r < 4; ++r) lacc[mi][r] = 0.f;
  f32x4 O[2][4];
#pragma unroll
  for (int mi = 0; mi < 2; ++mi)
#pragma unroll
    for (int dt = 0; dt < 4; ++dt) O[mi][dt] = (f32x4){0.f, 0.f, 0.f, 0.f};

  for (int kt = 0; kt < 10; ++kt) {
    const int kbase = kt * 64;
    // bias loads first (independent VMEM, latency overlaps staging)
    u16 bb[2][4][4];
#pragma unroll
    for (int mi = 0; mi < 2; ++mi)
#pragma unroll
      for (int nt = 0; nt < 4; ++nt)
#pragma unroll
        for (int r = 0; r < 4; ++r)
          bb[mi][nt][r] =
              bp[(size_t)brow[mi][r] * B_PITCH + kbase + nt * 16 + l15];

    // stage K [key][d] and V^T window [d][key] — 256 threads = two passes each
#pragma unroll
    for (int it = 0; it < 2; ++it) {
      int c = tid + it * 256;
      int rr = c >> 3, ko = (c & 7) << 3;
      int gk = kbase + rr;
      int4 kvv = make_int4(0, 0, 0, 0);
      if (gk < SEQ) kvv = *(const int4*)(kp + (size_t)gk * 768 + ko);
      *(int4*)&Ks[rr][ko] = kvv;
      *(int4*)&VTs[rr][ko] = *(const int4*)(vtp + (size_t)rr * VT_PITCH + kbase + ko);
    }
    __syncthreads();

    // S = Q K^T + bias  (bias as MFMA C-init; q pre-scaled by 0.125)
    // kf reads shared across both m-frags
    f32x4 s[2][4];
#pragma unroll
    for (int nt = 0; nt < 4; ++nt) {
      bf16x8 kf0 = *(const bf16x8*)(&Ks[nt * 16 + l15][quad * 8]);
      bf16x8 kf1 = *(const bf16x8*)(&Ks[nt * 16 + l15][32 + quad * 8]);
#pragma unroll
      for (int mi = 0; mi < 2; ++mi) {
        f32x4 z = (f32x4){bf2f(bb[mi][nt][0]), bf2f(bb[mi][nt][1]),
                          bf2f(bb[mi][nt][2]), bf2f(bb[mi][nt][3])};
        z = __builtin_amdgcn_mfma_f32_16x16x32_bf16(qf[mi][0], kf0, z, 0, 0, 0);
        z = __builtin_amdgcn_mfma_f32_16x16x32_bf16(qf[mi][1], kf1, z, 0, 0, 0);
        s[mi][nt] = z;
      }
    }

    // p = exp(s); truncate to bf16; l from truncated p (self-consistent)
    const bool full = (kbase + 64 <= SEQ);
#pragma unroll
    for (int mi = 0; mi < 2; ++mi)
#pragma unroll
      for (int nt = 0; nt < 4; ++nt) {
#pragma unroll
        for (int r = 0; r < 4; ++r) {
          float p = __expf(s[mi][nt][r]);
          unsigned int u = __float_as_uint(p);
          float pt = __uint_as_float(u & 0xFFFF0000u);
          if (full) lacc[mi][r] += pt;
          else lacc[mi][r] += ((kbase + nt * 16 + l15) < SEQ) ? pt : 0.f;
          Ps[w * 2 + mi][quad * 4 + r][((nt ^ quad) << 4) + l15] = (u16)(u >> 16);
        }
      }

    // O += P V  (vf reads shared across both m-frags)
#pragma unroll
    for (int ks = 0; ks < 2; ++ks) {
      int cc = (ks * 32 + quad * 8) ^ ((l15 >> 2) << 4);
      bf16x8 pf0 = *(const bf16x8*)(&Ps[w * 2 + 0][l15][cc]);
      bf16x8 pf1 = *(const bf16x8*)(&Ps[w * 2 + 1][l15][cc]);
#pragma unroll
      for (int dt = 0; dt < 4; ++dt) {
        bf16x8 vf = *(const bf16x8*)(&VTs[dt * 16 + l15][ks * 32 + quad * 8]);
        O[0][dt] = __builtin_amdgcn_mfma_f32_16x16x32_bf16(pf0, vf, O[0][dt], 0, 0, 0);
        O[1][dt] = __builtin_amdgcn_mfma_f32_16x16x32_bf16(pf1, vf, O[1][dt], 0, 0, 0);
      }
    }
    __syncthreads();  // protect Ks/VTs/Ps before next tile's staging
  }

  // epilogue: one cross-lane reduction of l per row, then normalize+store
#pragma unroll
  for (int mi = 0; mi < 2; ++mi)
#pragma unroll
    for (int r = 0; r < 4; ++r) {
      float l = lacc[mi][r];
      l += __shfl_xor(l, 1);
      l += __shfl_xor(l, 2);
      l += __shfl_xor(l, 4);
      l += __shfl_xor(l, 8);
      int row = qrow0 + mi * 16 + quad * 4 + r;
      if (row < SEQ) {
        float inv = 1.f / l;
#pragma unroll
        for (int dt = 0; dt < 4; ++dt)
          out[((size_t)(b * SEQ + row)) * 768 + h * 64 + dt * 16 + l15] =
              O[mi][dt][r] * inv;
      }
    }
}

extern "C" void kernel_launch(void* const* d_in, const int* in_sizes, int n_in,
                              void* d_out, int out_size, void* d_ws, size_t ws_size,
                              hipStream_t stream) {
  const float* hs = (const float*)d_in[0];
  const float* Wq = (const float*)d_in[1];
  const float* bq = (const float*)d_in[2];
  const float* Wk = (const float*)d_in[3];
  const float* Wv = (const float*)d_in[4];
  const float* bv = (const float*)d_in[5];
  const float* table = (const float*)d_in[6];
  const int* idx = (const int*)d_in[7];
  float* out = (float*)d_out;

  char* ws = (char*)d_ws;
  u16* qkv = (u16*)ws;                          // [0, 42541056)
  u16* WT = (u16*)(ws + 42541056);              // phase 1
  u16* Xb = (u16*)(ws + 46080000);              // phase 1
  u16* vT = (u16*)(ws + 42541056);              // phase 2 (over WT + Xb head)
  u16* biasm = (u16*)(ws + 58269696);           // phase 2 (over Xb tail)

  // phase 1: prep (transpose_w + cvt_x) -> GEMM
  hipLaunchKernelGGL(prep, dim3(5190), dim3(256), 0, stream, Wq, Wk, Wv, hs, WT, Xb);
  hipLaunchKernelGGL(qkv_gemm, dim3(240), dim3(512), 0, stream, Xb, WT, bq, bv, qkv);
  // phase 2: prep2 (transpose_v + bias_pre) -> attention
  hipLaunchKernelGGL(prep2, dim3(7884), dim3(256), 0, stream,
                     qkv + 2 * (size_t)QKV_STRIDE, vT, table, idx, biasm);
  hipLaunchKernelGGL(attn, dim3(192, 5), dim3(256), 0, stream, qkv, vT, biasm, out);
}

// Round 6
// 197.024 us; speedup vs baseline: 1.0241x; 1.0241x over previous
//
#include <hip/hip_runtime.h>
#include <hip/hip_bf16.h>

// TFData2VecVisionSelfAttention: B=16,S=577,D=768,H=12,HEAD=64. fp32 in/out.
// R15: attn = R13 structure (8 waves x 16q, 512 thr, VGPR~44, 33% occ — the
// proven-best TLP config) + ones-column MFMA row-sum: l = P x 1 computed by
// 2 extra MFMA/tile on the idle matrix pipe instead of ~96 VALU instrs/lane
// (truncate-AND + add + partial-tile masks) and the 16-shuffle epilogue.
// Enabler: prep2 writes bias = bf16(-100) for pad keys (exp -> 0), so padded
// columns self-mask and the full/partial logic disappears.
// R12/R14 lesson encoded: never trade occupancy for per-wave work here.
// qkv_gemm (R11 single-round 256x384/BK=32 triple-buffer) and prep unchanged.
// Workspace (bytes, phase-overlapped), total 67.1 MB:
//   qkv   [0, 42541056)                      3 x 9232x768 bf16 m-major (q,k,v)
//   WT    [42541056, 46080000)   phase 1     3x768x768 bf16
//   Xb    [46080000, 60260352)   phase 1     9232x768 bf16
//   vT    [42541056, 58269696)   phase 2     192x64x640 bf16 (over WT+Xb)
//   biasm [58269696, 67132416)   phase 2     12x577x640 bf16 (over Xb tail)

typedef __attribute__((ext_vector_type(8))) short bf16x8;   // 8 x bf16 (4 VGPRs)
typedef __attribute__((ext_vector_type(4))) float f32x4;
typedef unsigned short u16;

#define SEQ 577
#define MTOT 9232            // 16*577
#define QKV_STRIDE 7090176   // 9232*768 elements per q/k/v buffer
#define VT_PITCH 640         // keys per vT row (pad 577..639 zero-filled)
#define B_PITCH 640          // bias row pitch (pad = bf16(-100))

// fp32 -> bf16 round-to-nearest-even
static __device__ __forceinline__ u16 f2bf(float x) {
  unsigned int u = __float_as_uint(x);
  u = (u + 0x7FFFu + ((u >> 16) & 1u)) >> 16;
  return (u16)u;
}
static __device__ __forceinline__ float bf2f(u16 v) {
  return __uint_as_float(((unsigned int)v) << 16);
}

// async global->LDS, 16B per lane; LDS dest = wave-uniform base + lane*16
static __device__ __forceinline__ void gload_lds16(const void* g, void* l) {
  __builtin_amdgcn_global_load_lds(
      (const __attribute__((address_space(1))) unsigned int*)g,
      (__attribute__((address_space(3))) unsigned int*)l, 16, 0, 0);
}

// ---------------- prep: transpose_w (blocks 0..1727) + cvt_x (1728..5189) ----------------
__global__ __launch_bounds__(256) void prep(
    const float* __restrict__ Wq, const float* __restrict__ Wk,
    const float* __restrict__ Wv, const float* __restrict__ X,
    u16* __restrict__ WT, u16* __restrict__ Xb) {
  const int bid = blockIdx.x;
  if (bid < 1728) {
    __shared__ float t[32][33];
    const int z = bid / 576;
    const int rem = bid - z * 576;
    const int kx = rem % 24, ny = rem / 24;
    const float* W = (z == 0) ? Wq : (z == 1) ? Wk : Wv;
    int x = threadIdx.x & 31;
    int y = threadIdx.x >> 5;  // 0..7
    int k0 = kx * 32;
    int n0 = ny * 32;
#pragma unroll
    for (int i = 0; i < 4; ++i)
      t[y + i * 8][x] = W[(size_t)(k0 + y + i * 8) * 768 + n0 + x];
    __syncthreads();
    u16* o = WT + (size_t)z * 589824;
#pragma unroll
    for (int i = 0; i < 4; ++i)
      o[(size_t)(n0 + y + i * 8) * 768 + k0 + x] = f2bf(t[x][y + i * 8]);
  } else {
    size_t i = ((size_t)(bid - 1728) * 256 + threadIdx.x) * 8;
    if (i >= (size_t)MTOT * 768) return;
    const float4* xp = (const float4*)(X + i);
    float4 a = xp[0], b = xp[1];
    u16 pk[8] = {f2bf(a.x), f2bf(a.y), f2bf(a.z), f2bf(a.w),
                 f2bf(b.x), f2bf(b.y), f2bf(b.z), f2bf(b.w)};
    *(int4*)(Xb + i) = *(const int4*)pk;
  }
}

// ---------------- prep2: transpose_v (blocks 0..959) + bias_pre (960..7883) ----------------
__global__ __launch_bounds__(256) void prep2(
    const u16* __restrict__ v,      // v buffer, [m][768]
    u16* __restrict__ vT,           // [bh][64][640]
    const float* __restrict__ table, const int* __restrict__ idx,
    u16* __restrict__ biasm) {
  const int bid = blockIdx.x;
  const int tid = threadIdx.x;
  if (bid < 960) {
    const int tile = bid % 5;   // s0 = tile*128
    const int bh = bid / 5;     // 0..191
    const int b = bh / 12, h = bh % 12;
    __shared__ u16 T[128][64];
    const int s0 = tile * 128;
    const u16* vp = v + (size_t)b * SEQ * 768 + h * 64;
#pragma unroll
    for (int it = 0; it < 4; ++it) {
      int c = tid + it * 256;          // 1024 chunks of 16B
      int r = c >> 3, ko = (c & 7) << 3;
      int gs = s0 + r;
      int4 val = make_int4(0, 0, 0, 0);
      if (gs < SEQ) val = *(const int4*)(vp + (size_t)gs * 768 + ko);
      *(int4*)&T[r][ko ^ (((r >> 3) & 7) << 3)] = val;  // swizzled store
    }
    __syncthreads();
    u16* op = vT + (size_t)bh * 64 * VT_PITCH;
#pragma unroll
    for (int it = 0; it < 4; ++it) {
      int c = tid + it * 256;          // d = c>>4, so = (c&15)*8
      int d = c >> 4, so = (c & 15) << 3;
      u16 tmp[8];
#pragma unroll
      for (int j = 0; j < 8; ++j) {
        int rr = so + j;
        tmp[j] = T[rr][d ^ (((rr >> 3) & 7) << 3)];
      }
      *(int4*)(op + (size_t)d * VT_PITCH + s0 + so) = *(const int4*)tmp;
    }
  } else {
    const int r = bid - 960;        // 0..6923
    const int q = r % 577;
    const int h = r / 577;
    for (int k = tid; k < B_PITCH; k += 256) {
      u16 vv = 0xC2C8;  // bf16(-100): pad keys self-mask (exp -> 0)
      if (k < SEQ) vv = f2bf(table[idx[q * SEQ + k] * 12 + h]);
      biasm[((size_t)h * SEQ + q) * B_PITCH + k] = vv;
    }
  }
}

// ---------------- fused QKV GEMM: 256x384 tile, BK=32, 8 waves, triple-buffer ----------------
// Grid: 37 M-tiles x 6 N-tiles = 222 blocks (<=256 CUs -> one round).
// N = 3 outputs x 768; nt&1 selects 384-col half, nt>>1 selects q/k/v.
// XCD pinning: bid&7 groups same-mt blocks on one XCD (shared A panel in L2).
// LDS: SAB[3][A 256x32 | B 384x32] bf16 = 120 KiB. 64B rows; chunk16 swizzle
// chunk ^= (row>>1)&3 (uniform bank spread on ds_read_b128). Stage tile t+2
// into buf (t+2)%3 spread {3,2} over the 2 phases; boundary s_waitcnt vmcnt(5).
#define G_STAGE_A(BS, KT, U)                                                   \
  gload_lds16(aptr[(U)] + (KT) * 32, &SAB[(BS)][((U) * 128 + w16) * 32])
#define G_STAGE_B(BS, KT, U)                                                   \
  gload_lds16(bptr + (size_t)(U) * 128 * 768 + (KT) * 32,                      \
              &SAB[(BS)][8192 + ((U) * 128 + w16) * 32])

__global__ __launch_bounds__(512, 2) void qkv_gemm(
    const u16* __restrict__ Xb,   // [9232][768] bf16
    const u16* __restrict__ WT,   // [3][768][768] n-major bf16
    const float* __restrict__ bq, const float* __restrict__ bv,
    u16* __restrict__ qkv) {
  const int bid = blockIdx.x;
  const int x = bid & 7;
  const int l = bid >> 3;
  const int mt = x + 8 * (l / 6);          // same-mt blocks land on one XCD
  if (mt >= 37) return;
  const int nt = l % 6;
  const int m0 = mt * 256;
  const int widx = nt >> 1;                // 0=q, 1=k, 2=v
  const int nb = (nt & 1) * 384;           // col base within [0,768)

  const int tid = threadIdx.x;
  const int lane = tid & 63;
  const int w = tid >> 6;                  // 0..7
  const int wm2 = w >> 2;                  // 0..1 (M half: 128 rows)
  const int wn = w & 3;                    // 0..3 (N quarter: 96 cols)
  const int quad = lane >> 4;
  const int l15 = lane & 15;
  const int w16 = w * 16;

  __shared__ u16 SAB[3][20480];            // per buf: A[256][32] | B[384][32]

  // ---- staging addressing: lane covers (row = w16 + lane>>2, chunk = lane&3)
  // source chunk pre-swizzled: ce = (lane&3) ^ ((lane>>3)&3)
  const int srow = w16 + (lane >> 2);
  const int ce8 = (((lane & 3) ^ ((lane >> 3) & 3))) * 8;
  const u16* aptr[2];
#pragma unroll
  for (int u = 0; u < 2; ++u) {
    int rr = m0 + u * 128 + srow;
    if (rr > MTOT - 1) rr = MTOT - 1;      // clamped rows: garbage, not stored
    aptr[u] = Xb + (size_t)rr * 768 + ce8;
  }
  const u16* bptr =
      WT + (size_t)widx * 589824 + (size_t)(nb + srow) * 768 + ce8;

  // ---- ds_read addressing (unswizzle): chunk = quad ^ ((l15>>1)&3)
  const int ca8 = (quad ^ ((l15 >> 1) & 3)) * 8;   // elems

  f32x4 acc[8][6];
#pragma unroll
  for (int i = 0; i < 8; ++i)
#pragma unroll
    for (int j = 0; j < 6; ++j) acc[i][j] = (f32x4){0.f, 0.f, 0.f, 0.f};
  bf16x8 af[4], bfr[6];

  // ---- prologue: stage tiles 0 and 1 fully (5 units each) ----
  G_STAGE_A(0, 0, 0); G_STAGE_A(0, 0, 1);
  G_STAGE_B(0, 0, 0); G_STAGE_B(0, 0, 1); G_STAGE_B(0, 0, 2);
  G_STAGE_A(1, 1, 0); G_STAGE_A(1, 1, 1);
  G_STAGE_B(1, 1, 0); G_STAGE_B(1, 1, 1); G_STAGE_B(1, 1, 2);
  asm volatile("s_waitcnt vmcnt(5)" ::: "memory");  // tile0 landed; 5 in flight
  __builtin_amdgcn_s_barrier();
  asm volatile("" ::: "memory");

  int bs = 0, bt2 = 2;
  for (int t = 0; t < 24; ++t) {
    // ---- P0: quadrant mh0 (rows wm2*128 + 0..63) x all 6 n-frags ----
#pragma unroll
    for (int i = 0; i < 4; ++i)
      af[i] = *(const bf16x8*)&SAB[bs][(wm2 * 128 + i * 16 + l15) * 32 + ca8];
#pragma unroll
    for (int j = 0; j < 6; ++j)
      bfr[j] = *(const bf16x8*)&SAB[bs][8192 + (wn * 96 + j * 16 + l15) * 32 + ca8];
    if (t <= 21) { G_STAGE_A(bt2, t + 2, 0); G_STAGE_A(bt2, t + 2, 1); G_STAGE_B(bt2, t + 2, 0); }
    asm volatile("" ::: "memory");
    __builtin_amdgcn_s_barrier();
    asm volatile("s_waitcnt lgkmcnt(0)" ::: "memory");
    __builtin_amdgcn_s_setprio(1);
#pragma unroll
    for (int j = 0; j < 6; ++j)
#pragma unroll
      for (int i = 0; i < 4; ++i)
        acc[i][j] = __builtin_amdgcn_mfma_f32_16x16x32_bf16(af[i], bfr[j],
                                                            acc[i][j], 0, 0, 0);
    __builtin_amdgcn_s_setprio(0);
    asm volatile("" ::: "memory");
    __builtin_amdgcn_s_barrier();
    asm volatile("" ::: "memory");
    // ---- P1: quadrant mh1 (rows wm2*128 + 64..127) x all 6 n-frags ----
#pragma unroll
    for (int i = 0; i < 4; ++i)
      af[i] = *(const bf16x8*)&SAB[bs][(wm2 * 128 + 64 + i * 16 + l15) * 32 + ca8];
#pragma unroll
    for (int j = 0; j < 6; ++j)
      bfr[j] = *(const bf16x8*)&SAB[bs][8192 + (wn * 96 + j * 16 + l15) * 32 + ca8];
    if (t <= 21) { G_STAGE_B(bt2, t + 2, 1); G_STAGE_B(bt2, t + 2, 2); }
    asm volatile("" ::: "memory");
    __builtin_amdgcn_s_barrier();
    asm volatile("s_waitcnt lgkmcnt(0)" ::: "memory");
    __builtin_amdgcn_s_setprio(1);
#pragma unroll
    for (int j = 0; j < 6; ++j)
#pragma unroll
      for (int i = 0; i < 4; ++i)
        acc[4 + i][j] = __builtin_amdgcn_mfma_f32_16x16x32_bf16(
            af[i], bfr[j], acc[4 + i][j], 0, 0, 0);
    __builtin_amdgcn_s_setprio(0);
    // boundary: counted wait -> tile t+1 landed; t+2's 5 units stay in flight
    if (t < 22) {
      asm volatile("s_waitcnt vmcnt(5)" ::: "memory");
    } else if (t == 22) {
      asm volatile("s_waitcnt vmcnt(0)" ::: "memory");
    }
    asm volatile("" ::: "memory");
    __builtin_amdgcn_s_barrier();
    asm volatile("" ::: "memory");
    bs = (bs == 2) ? 0 : bs + 1;
    bt2 = (bt2 == 2) ? 0 : bt2 + 1;
  }

  // ---- epilogue: scale+bias, LDS-staged (128x384 halves), full-row stores ----
  const float scale = (widx == 0) ? 0.125f : 1.0f;
  float biasv[6];
#pragma unroll
  for (int nf = 0; nf < 6; ++nf) {
    int n = nb + wn * 96 + nf * 16 + l15;
    biasv[nf] = (widx == 0) ? bq[n] * 0.125f : (widx == 2) ? bv[n] : 0.f;
  }
  u16* E = &SAB[0][0];                     // 128 x 384 u16 (96 KB)
  u16* ob = qkv + (size_t)widx * QKV_STRIDE + nb;
#pragma unroll
  for (int half = 0; half < 2; ++half) {
    if (wm2 == half) {
#pragma unroll
      for (int mf = 0; mf < 8; ++mf)
#pragma unroll
        for (int nf = 0; nf < 6; ++nf)
#pragma unroll
          for (int r = 0; r < 4; ++r) {
            int rowl = mf * 16 + quad * 4 + r;           // 0..127
            int col = wn * 96 + nf * 16 + l15;           // 0..383
            int colr = (((col >> 4) ^ quad) << 4) | (col & 15);
            E[rowl * 384 + colr] = f2bf(acc[mf][nf][r] * scale + biasv[nf]);
          }
    }
    __syncthreads();
#pragma unroll 4
    for (int it = 0; it < 12; ++it) {
      int c = it * 512 + tid;              // 128 rows x 48 chunks
      int row = c / 48;
      int ch = c - row * 48;
      int m = m0 + half * 128 + row;
      if (m < MTOT) {
        int g = (ch >> 1) ^ ((row >> 2) & 3);
        int colr = (g << 4) + (ch & 1) * 8;
        *(int4*)(ob + (size_t)m * 768 + ch * 8) = *(const int4*)&E[row * 384 + colr];
      }
    }
    __syncthreads();
  }
}

// ---------------- flash attention (no-max softmax), 512 threads / 128 q-rows ----------------
// grid (bh=192, qt=5): 192%8==0 pins all qt-blocks of one (b,h) to one XCD.
// R15: l = P x ones via 2 extra MFMA/tile (matrix pipe ~14% busy) replacing
// the per-lane truncate+add chain and the epilogue shuffle reduce. Pad keys
// carry bias=-100 so they self-mask (no full/partial logic).
__global__ __launch_bounds__(512) void attn(
    const u16* __restrict__ qk, const u16* __restrict__ vT,
    const u16* __restrict__ biasm, float* __restrict__ out) {
  const int bh = blockIdx.x;  // b*12+h
  const int qt = blockIdx.y;  // 0..4
  const int b = bh / 12, h = bh - b * 12;
  const int tid = threadIdx.x;
  const int lane = tid & 63;
  const int w = tid >> 6;     // 0..7
  const int quad = lane >> 4;
  const int l15 = lane & 15;

  const u16* qp = qk + (size_t)b * SEQ * 768 + h * 64;  // row stride 768
  const u16* kp = qp + (size_t)QKV_STRIDE;
  const u16* vtp = vT + (size_t)bh * 64 * VT_PITCH;
  const u16* bp = biasm + (size_t)h * SEQ * B_PITCH;

  __shared__ u16 Ks[64][72];     // [key][d]
  __shared__ u16 VTs[64][72];    // [d][key]
  __shared__ u16 Ps[8][16][72];  // per-wave P tile, XOR-swizzled chunks

  const int qrow0 = qt * 128 + w * 16;

  bf16x8 qf[2];
  {
    int row = qrow0 + l15;
    if (row > 576) row = 576;  // clamp; clamped rows never stored
    qf[0] = *(const bf16x8*)(qp + (size_t)row * 768 + quad * 8);
    qf[1] = *(const bf16x8*)(qp + (size_t)row * 768 + 32 + quad * 8);
  }
  int brow[4];
#pragma unroll
  for (int r = 0; r < 4; ++r) {
    int rr = qrow0 + quad * 4 + r;
    if (rr > 576) rr = 576;
    brow[r] = rr;
  }

  const short one_bf = (short)0x3F80;      // bf16 1.0
  const bf16x8 vones = {one_bf, one_bf, one_bf, one_bf,
                        one_bf, one_bf, one_bf, one_bf};

  f32x4 Ol = (f32x4){0.f, 0.f, 0.f, 0.f};  // row sums l (per quad-row)
  f32x4 O[4];
#pragma unroll
  for (int dt = 0; dt < 4; ++dt) O[dt] = (f32x4){0.f, 0.f, 0.f, 0.f};

  for (int kt = 0; kt < 10; ++kt) {
    const int kbase = kt * 64;
    // bias loads first (independent VMEM, latency overlaps staging)
    u16 bb[4][4];
#pragma unroll
    for (int nt = 0; nt < 4; ++nt)
#pragma unroll
      for (int r = 0; r < 4; ++r)
        bb[nt][r] = bp[(size_t)brow[r] * B_PITCH + kbase + nt * 16 + l15];

    // stage K [key][d] and V^T window [d][key] — 512 threads = one pass each
    {
      int rr = tid >> 3, ko = (tid & 7) << 3;
      int gk = kbase + rr;
      int4 kvv = make_int4(0, 0, 0, 0);
      if (gk < SEQ) kvv = *(const int4*)(kp + (size_t)gk * 768 + ko);
      *(int4*)&Ks[rr][ko] = kvv;
      *(int4*)&VTs[rr][ko] = *(const int4*)(vtp + (size_t)rr * VT_PITCH + kbase + ko);
    }
    __syncthreads();

    // S = Q K^T + bias  (bias as MFMA C-init; q pre-scaled by 0.125;
    // pad keys: K=0, bias=-100 -> exp ~ 0, self-masked)
    f32x4 s[4];
#pragma unroll
    for (int nt = 0; nt < 4; ++nt) {
      f32x4 z = (f32x4){bf2f(bb[nt][0]), bf2f(bb[nt][1]),
                        bf2f(bb[nt][2]), bf2f(bb[nt][3])};
      bf16x8 kf0 = *(const bf16x8*)(&Ks[nt * 16 + l15][quad * 8]);
      bf16x8 kf1 = *(const bf16x8*)(&Ks[nt * 16 + l15][32 + quad * 8]);
      z = __builtin_amdgcn_mfma_f32_16x16x32_bf16(qf[0], kf0, z, 0, 0, 0);
      z = __builtin_amdgcn_mfma_f32_16x16x32_bf16(qf[1], kf1, z, 0, 0, 0);
      s[nt] = z;
    }

    // p = exp(s); truncate to bf16 into Ps (l comes from ones-MFMA below)
#pragma unroll
    for (int nt = 0; nt < 4; ++nt) {
#pragma unroll
      for (int r = 0; r < 4; ++r) {
        float p = __expf(s[nt][r]);
        unsigned int u = __float_as_uint(p);
        Ps[w][quad * 4 + r][((nt ^ quad) << 4) + l15] = (u16)(u >> 16);
      }
    }

    // O += P V; Ol += P x ones (row-sum on the matrix pipe)
#pragma unroll
    for (int ks = 0; ks < 2; ++ks) {
      int cc = (ks * 32 + quad * 8) ^ ((l15 >> 2) << 4);
      bf16x8 pf = *(const bf16x8*)(&Ps[w][l15][cc]);
#pragma unroll
      for (int dt = 0; dt < 4; ++dt) {
        bf16x8 vf = *(const bf16x8*)(&VTs[dt * 16 + l15][ks * 32 + quad * 8]);
        O[dt] = __builtin_amdgcn_mfma_f32_16x16x32_bf16(pf, vf, O[dt], 0, 0, 0);
      }
      Ol = __builtin_amdgcn_mfma_f32_16x16x32_bf16(pf, vones, Ol, 0, 0, 0);
    }
    __syncthreads();  // protect Ks/VTs/Ps before next tile's staging
  }

  // epilogue: l available per-lane from the ones-MFMA (no reduction needed)
#pragma unroll
  for (int r = 0; r < 4; ++r) {
    int row = qrow0 + quad * 4 + r;
    if (row < SEQ) {
      float inv = 1.f / Ol[r];
#pragma unroll
      for (int dt = 0; dt < 4; ++dt)
        out[((size_t)(b * SEQ + row)) * 768 + h * 64 + dt * 16 + l15] = O[dt][r] * inv;
    }
  }
}

extern "C" void kernel_launch(void* const* d_in, const int* in_sizes, int n_in,
                              void* d_out, int out_size, void* d_ws, size_t ws_size,
                              hipStream_t stream) {
  const float* hs = (const float*)d_in[0];
  const float* Wq = (const float*)d_in[1];
  const float* bq = (const float*)d_in[2];
  const float* Wk = (const float*)d_in[3];
  const float* Wv = (const float*)d_in[4];
  const float* bv = (const float*)d_in[5];
  const float* table = (const float*)d_in[6];
  const int* idx = (const int*)d_in[7];
  float* out = (float*)d_out;

  char* ws = (char*)d_ws;
  u16* qkv = (u16*)ws;                          // [0, 42541056)
  u16* WT = (u16*)(ws + 42541056);              // phase 1
  u16* Xb = (u16*)(ws + 46080000);              // phase 1
  u16* vT = (u16*)(ws + 42541056);              // phase 2 (over WT + Xb head)
  u16* biasm = (u16*)(ws + 58269696);           // phase 2 (over Xb tail)

  // phase 1: prep (transpose_w + cvt_x) -> GEMM
  hipLaunchKernelGGL(prep, dim3(5190), dim3(256), 0, stream, Wq, Wk, Wv, hs, WT, Xb);
  hipLaunchKernelGGL(qkv_gemm, dim3(240), dim3(512), 0, stream, Xb, WT, bq, bv, qkv);
  // phase 2: prep2 (transpose_v + bias_pre) -> attention
  hipLaunchKernelGGL(prep2, dim3(7884), dim3(256), 0, stream,
                     qkv + 2 * (size_t)QKV_STRIDE, vT, table, idx, biasm);
  hipLaunchKernelGGL(attn, dim3(192, 5), dim3(512), 0, stream, qkv, vT, biasm, out);
}

// Round 8
// 195.401 us; speedup vs baseline: 1.0326x; 1.0083x over previous
//
#include <hip/hip_runtime.h>
#include <hip/hip_bf16.h>

// TFData2VecVisionSelfAttention: B=16,S=577,D=768,H=12,HEAD=64. fp32 in/out.
// R17 = R16 with the compile fix (__exp2f -> exp2f, lowers to v_exp_f32):
//  - prep2 bias gather h-vectorized: one block per q-row reads idx ONCE
//    (was 12x redundant), fetches table[idx*12..+11] as 3 coalesced float4
//    (48B contiguous) and writes 12 coalesced u16 plane-stores. 6924->577
//    blocks, ~3x fewer VMEM requests.
//  - exp2 folding: q-scale = 0.125*log2e baked in qkv_gemm; biasm values
//    pre-multiplied by log2e (pad = -144); attn uses exp2f -> drops 32
//    v_mul per lane per tile. No structural change to gemm/attn.
// R12/R14 lesson: attn occupancy (VGPR 44, 4 blocks/CU) is sacred.
// Workspace (bytes, phase-overlapped), total 67.1 MB:
//   qkv   [0, 42541056)                      3 x 9232x768 bf16 m-major (q,k,v)
//   WT    [42541056, 46080000)   phase 1     3x768x768 bf16
//   Xb    [46080000, 60260352)   phase 1     9232x768 bf16
//   vT    [42541056, 58269696)   phase 2     192x64x640 bf16 (over WT+Xb)
//   biasm [58269696, 67132416)   phase 2     12x577x640 bf16 (over Xb tail)

typedef __attribute__((ext_vector_type(8))) short bf16x8;   // 8 x bf16 (4 VGPRs)
typedef __attribute__((ext_vector_type(4))) float f32x4;
typedef unsigned short u16;

#define SEQ 577
#define MTOT 9232            // 16*577
#define QKV_STRIDE 7090176   // 9232*768 elements per q/k/v buffer
#define VT_PITCH 640         // keys per vT row (pad 577..639 zero-filled)
#define B_PITCH 640          // bias row pitch (pad = bf16(-144))
#define QSCALE 0.18033688f   // 0.125 * log2(e)
#define LOG2E 1.44269504f

// fp32 -> bf16 round-to-nearest-even
static __device__ __forceinline__ u16 f2bf(float x) {
  unsigned int u = __float_as_uint(x);
  u = (u + 0x7FFFu + ((u >> 16) & 1u)) >> 16;
  return (u16)u;
}
static __device__ __forceinline__ float bf2f(u16 v) {
  return __uint_as_float(((unsigned int)v) << 16);
}

// async global->LDS, 16B per lane; LDS dest = wave-uniform base + lane*16
static __device__ __forceinline__ void gload_lds16(const void* g, void* l) {
  __builtin_amdgcn_global_load_lds(
      (const __attribute__((address_space(1))) unsigned int*)g,
      (__attribute__((address_space(3))) unsigned int*)l, 16, 0, 0);
}

// ---------------- prep: transpose_w (blocks 0..1727) + cvt_x (1728..5189) ----------------
__global__ __launch_bounds__(256) void prep(
    const float* __restrict__ Wq, const float* __restrict__ Wk,
    const float* __restrict__ Wv, const float* __restrict__ X,
    u16* __restrict__ WT, u16* __restrict__ Xb) {
  const int bid = blockIdx.x;
  if (bid < 1728) {
    __shared__ float t[32][33];
    const int z = bid / 576;
    const int rem = bid - z * 576;
    const int kx = rem % 24, ny = rem / 24;
    const float* W = (z == 0) ? Wq : (z == 1) ? Wk : Wv;
    int x = threadIdx.x & 31;
    int y = threadIdx.x >> 5;  // 0..7
    int k0 = kx * 32;
    int n0 = ny * 32;
#pragma unroll
    for (int i = 0; i < 4; ++i)
      t[y + i * 8][x] = W[(size_t)(k0 + y + i * 8) * 768 + n0 + x];
    __syncthreads();
    u16* o = WT + (size_t)z * 589824;
#pragma unroll
    for (int i = 0; i < 4; ++i)
      o[(size_t)(n0 + y + i * 8) * 768 + k0 + x] = f2bf(t[x][y + i * 8]);
  } else {
    size_t i = ((size_t)(bid - 1728) * 256 + threadIdx.x) * 8;
    if (i >= (size_t)MTOT * 768) return;
    const float4* xp = (const float4*)(X + i);
    float4 a = xp[0], b = xp[1];
    u16 pk[8] = {f2bf(a.x), f2bf(a.y), f2bf(a.z), f2bf(a.w),
                 f2bf(b.x), f2bf(b.y), f2bf(b.z), f2bf(b.w)};
    *(int4*)(Xb + i) = *(const int4*)pk;
  }
}

// ---------------- prep2: transpose_v (blocks 0..959) + bias_pre (960..1536) ----------------
__global__ __launch_bounds__(256) void prep2(
    const u16* __restrict__ v,      // v buffer, [m][768]
    u16* __restrict__ vT,           // [bh][64][640]
    const float* __restrict__ table, const int* __restrict__ idx,
    u16* __restrict__ biasm) {
  const int bid = blockIdx.x;
  const int tid = threadIdx.x;
  if (bid < 960) {
    const int tile = bid % 5;   // s0 = tile*128
    const int bh = bid / 5;     // 0..191
    const int b = bh / 12, h = bh % 12;
    __shared__ u16 T[128][64];
    const int s0 = tile * 128;
    const u16* vp = v + (size_t)b * SEQ * 768 + h * 64;
#pragma unroll
    for (int it = 0; it < 4; ++it) {
      int c = tid + it * 256;          // 1024 chunks of 16B
      int r = c >> 3, ko = (c & 7) << 3;
      int gs = s0 + r;
      int4 val = make_int4(0, 0, 0, 0);
      if (gs < SEQ) val = *(const int4*)(vp + (size_t)gs * 768 + ko);
      *(int4*)&T[r][ko ^ (((r >> 3) & 7) << 3)] = val;  // swizzled store
    }
    __syncthreads();
    u16* op = vT + (size_t)bh * 64 * VT_PITCH;
#pragma unroll
    for (int it = 0; it < 4; ++it) {
      int c = tid + it * 256;          // d = c>>4, so = (c&15)*8
      int d = c >> 4, so = (c & 15) << 3;
      u16 tmp[8];
#pragma unroll
      for (int j = 0; j < 8; ++j) {
        int rr = so + j;
        tmp[j] = T[rr][d ^ (((rr >> 3) & 7) << 3)];
      }
      *(int4*)(op + (size_t)d * VT_PITCH + s0 + so) = *(const int4*)tmp;
    }
  } else {
    // bias gather, h-vectorized: one block per q-row. idx read once per
    // (q,k); table row (12 floats = 48B, 16B-aligned) via 3x float4; values
    // pre-scaled by log2e for attn's exp2. 12 coalesced u16 plane-stores.
    const int q = bid - 960;        // 0..576
    const int* idxq = idx + q * SEQ;
    const u16 pad = f2bf(-144.0f);
    for (int k = tid; k < B_PITCH; k += 256) {
      u16 vv[12];
      if (k < SEQ) {
        const float4* tp = (const float4*)(table + (size_t)idxq[k] * 12);
        float4 t0 = tp[0], t1 = tp[1], t2 = tp[2];
        vv[0] = f2bf(t0.x * LOG2E);  vv[1] = f2bf(t0.y * LOG2E);
        vv[2] = f2bf(t0.z * LOG2E);  vv[3] = f2bf(t0.w * LOG2E);
        vv[4] = f2bf(t1.x * LOG2E);  vv[5] = f2bf(t1.y * LOG2E);
        vv[6] = f2bf(t1.z * LOG2E);  vv[7] = f2bf(t1.w * LOG2E);
        vv[8] = f2bf(t2.x * LOG2E);  vv[9] = f2bf(t2.y * LOG2E);
        vv[10] = f2bf(t2.z * LOG2E); vv[11] = f2bf(t2.w * LOG2E);
      } else {
#pragma unroll
        for (int h = 0; h < 12; ++h) vv[h] = pad;  // pad keys self-mask
      }
#pragma unroll
      for (int h = 0; h < 12; ++h)
        biasm[((size_t)h * SEQ + q) * B_PITCH + k] = vv[h];
    }
  }
}

// ---------------- fused QKV GEMM: 256x384 tile, BK=32, 8 waves, triple-buffer ----------------
// Grid: 37 M-tiles x 6 N-tiles = 222 blocks (<=256 CUs -> one round).
// N = 3 outputs x 768; nt&1 selects 384-col half, nt>>1 selects q/k/v.
// XCD pinning: bid&7 groups same-mt blocks on one XCD (shared A panel in L2).
// LDS: SAB[3][A 256x32 | B 384x32] bf16 = 120 KiB. 64B rows; chunk16 swizzle
// chunk ^= (row>>1)&3 (uniform bank spread on ds_read_b128). Stage tile t+2
// into buf (t+2)%3 spread {3,2} over the 2 phases; boundary s_waitcnt vmcnt(5).
#define G_STAGE_A(BS, KT, U)                                                   \
  gload_lds16(aptr[(U)] + (KT) * 32, &SAB[(BS)][((U) * 128 + w16) * 32])
#define G_STAGE_B(BS, KT, U)                                                   \
  gload_lds16(bptr + (size_t)(U) * 128 * 768 + (KT) * 32,                      \
              &SAB[(BS)][8192 + ((U) * 128 + w16) * 32])

__global__ __launch_bounds__(512, 2) void qkv_gemm(
    const u16* __restrict__ Xb,   // [9232][768] bf16
    const u16* __restrict__ WT,   // [3][768][768] n-major bf16
    const float* __restrict__ bq, const float* __restrict__ bv,
    u16* __restrict__ qkv) {
  const int bid = blockIdx.x;
  const int x = bid & 7;
  const int l = bid >> 3;
  const int mt = x + 8 * (l / 6);          // same-mt blocks land on one XCD
  if (mt >= 37) return;
  const int nt = l % 6;
  const int m0 = mt * 256;
  const int widx = nt >> 1;                // 0=q, 1=k, 2=v
  const int nb = (nt & 1) * 384;           // col base within [0,768)

  const int tid = threadIdx.x;
  const int lane = tid & 63;
  const int w = tid >> 6;                  // 0..7
  const int wm2 = w >> 2;                  // 0..1 (M half: 128 rows)
  const int wn = w & 3;                    // 0..3 (N quarter: 96 cols)
  const int quad = lane >> 4;
  const int l15 = lane & 15;
  const int w16 = w * 16;

  __shared__ u16 SAB[3][20480];            // per buf: A[256][32] | B[384][32]

  // ---- staging addressing: lane covers (row = w16 + lane>>2, chunk = lane&3)
  // source chunk pre-swizzled: ce = (lane&3) ^ ((lane>>3)&3)
  const int srow = w16 + (lane >> 2);
  const int ce8 = (((lane & 3) ^ ((lane >> 3) & 3))) * 8;
  const u16* aptr[2];
#pragma unroll
  for (int u = 0; u < 2; ++u) {
    int rr = m0 + u * 128 + srow;
    if (rr > MTOT - 1) rr = MTOT - 1;      // clamped rows: garbage, not stored
    aptr[u] = Xb + (size_t)rr * 768 + ce8;
  }
  const u16* bptr =
      WT + (size_t)widx * 589824 + (size_t)(nb + srow) * 768 + ce8;

  // ---- ds_read addressing (unswizzle): chunk = quad ^ ((l15>>1)&3)
  const int ca8 = (quad ^ ((l15 >> 1) & 3)) * 8;   // elems

  f32x4 acc[8][6];
#pragma unroll
  for (int i = 0; i < 8; ++i)
#pragma unroll
    for (int j = 0; j < 6; ++j) acc[i][j] = (f32x4){0.f, 0.f, 0.f, 0.f};
  bf16x8 af[4], bfr[6];

  // ---- prologue: stage tiles 0 and 1 fully (5 units each) ----
  G_STAGE_A(0, 0, 0); G_STAGE_A(0, 0, 1);
  G_STAGE_B(0, 0, 0); G_STAGE_B(0, 0, 1); G_STAGE_B(0, 0, 2);
  G_STAGE_A(1, 1, 0); G_STAGE_A(1, 1, 1);
  G_STAGE_B(1, 1, 0); G_STAGE_B(1, 1, 1); G_STAGE_B(1, 1, 2);
  asm volatile("s_waitcnt vmcnt(5)" ::: "memory");  // tile0 landed; 5 in flight
  __builtin_amdgcn_s_barrier();
  asm volatile("" ::: "memory");

  int bs = 0, bt2 = 2;
  for (int t = 0; t < 24; ++t) {
    // ---- P0: quadrant mh0 (rows wm2*128 + 0..63) x all 6 n-frags ----
#pragma unroll
    for (int i = 0; i < 4; ++i)
      af[i] = *(const bf16x8*)&SAB[bs][(wm2 * 128 + i * 16 + l15) * 32 + ca8];
#pragma unroll
    for (int j = 0; j < 6; ++j)
      bfr[j] = *(const bf16x8*)&SAB[bs][8192 + (wn * 96 + j * 16 + l15) * 32 + ca8];
    if (t <= 21) { G_STAGE_A(bt2, t + 2, 0); G_STAGE_A(bt2, t + 2, 1); G_STAGE_B(bt2, t + 2, 0); }
    asm volatile("" ::: "memory");
    __builtin_amdgcn_s_barrier();
    asm volatile("s_waitcnt lgkmcnt(0)" ::: "memory");
    __builtin_amdgcn_s_setprio(1);
#pragma unroll
    for (int j = 0; j < 6; ++j)
#pragma unroll
      for (int i = 0; i < 4; ++i)
        acc[i][j] = __builtin_amdgcn_mfma_f32_16x16x32_bf16(af[i], bfr[j],
                                                            acc[i][j], 0, 0, 0);
    __builtin_amdgcn_s_setprio(0);
    asm volatile("" ::: "memory");
    __builtin_amdgcn_s_barrier();
    asm volatile("" ::: "memory");
    // ---- P1: quadrant mh1 (rows wm2*128 + 64..127) x all 6 n-frags ----
#pragma unroll
    for (int i = 0; i < 4; ++i)
      af[i] = *(const bf16x8*)&SAB[bs][(wm2 * 128 + 64 + i * 16 + l15) * 32 + ca8];
#pragma unroll
    for (int j = 0; j < 6; ++j)
      bfr[j] = *(const bf16x8*)&SAB[bs][8192 + (wn * 96 + j * 16 + l15) * 32 + ca8];
    if (t <= 21) { G_STAGE_B(bt2, t + 2, 1); G_STAGE_B(bt2, t + 2, 2); }
    asm volatile("" ::: "memory");
    __builtin_amdgcn_s_barrier();
    asm volatile("s_waitcnt lgkmcnt(0)" ::: "memory");
    __builtin_amdgcn_s_setprio(1);
#pragma unroll
    for (int j = 0; j < 6; ++j)
#pragma unroll
      for (int i = 0; i < 4; ++i)
        acc[4 + i][j] = __builtin_amdgcn_mfma_f32_16x16x32_bf16(
            af[i], bfr[j], acc[4 + i][j], 0, 0, 0);
    __builtin_amdgcn_s_setprio(0);
    // boundary: counted wait -> tile t+1 landed; t+2's 5 units stay in flight
    if (t < 22) {
      asm volatile("s_waitcnt vmcnt(5)" ::: "memory");
    } else if (t == 22) {
      asm volatile("s_waitcnt vmcnt(0)" ::: "memory");
    }
    asm volatile("" ::: "memory");
    __builtin_amdgcn_s_barrier();
    asm volatile("" ::: "memory");
    bs = (bs == 2) ? 0 : bs + 1;
    bt2 = (bt2 == 2) ? 0 : bt2 + 1;
  }

  // ---- epilogue: scale+bias, LDS-staged (128x384 halves), full-row stores ----
  // q-scale folds 0.125 * log2(e) so attn can use exp2 directly.
  const float scale = (widx == 0) ? QSCALE : 1.0f;
  float biasv[6];
#pragma unroll
  for (int nf = 0; nf < 6; ++nf) {
    int n = nb + wn * 96 + nf * 16 + l15;
    biasv[nf] = (widx == 0) ? bq[n] * QSCALE : (widx == 2) ? bv[n] : 0.f;
  }
  u16* E = &SAB[0][0];                     // 128 x 384 u16 (96 KB)
  u16* ob = qkv + (size_t)widx * QKV_STRIDE + nb;
#pragma unroll
  for (int half = 0; half < 2; ++half) {
    if (wm2 == half) {
#pragma unroll
      for (int mf = 0; mf < 8; ++mf)
#pragma unroll
        for (int nf = 0; nf < 6; ++nf)
#pragma unroll
          for (int r = 0; r < 4; ++r) {
            int rowl = mf * 16 + quad * 4 + r;           // 0..127
            int col = wn * 96 + nf * 16 + l15;           // 0..383
            int colr = (((col >> 4) ^ quad) << 4) | (col & 15);
            E[rowl * 384 + colr] = f2bf(acc[mf][nf][r] * scale + biasv[nf]);
          }
    }
    __syncthreads();
#pragma unroll 4
    for (int it = 0; it < 12; ++it) {
      int c = it * 512 + tid;              // 128 rows x 48 chunks
      int row = c / 48;
      int ch = c - row * 48;
      int m = m0 + half * 128 + row;
      if (m < MTOT) {
        int g = (ch >> 1) ^ ((row >> 2) & 3);
        int colr = (g << 4) + (ch & 1) * 8;
        *(int4*)(ob + (size_t)m * 768 + ch * 8) = *(const int4*)&E[row * 384 + colr];
      }
    }
    __syncthreads();
  }
}

// ---------------- flash attention (no-max softmax), 512 threads / 128 q-rows ----------------
// grid (bh=192, qt=5): 192%8==0 pins all qt-blocks of one (b,h) to one XCD.
// R15: l = P x ones via 2 extra MFMA/tile. R17: exp2f (scales pre-folded).
// Pad keys carry bias=-144 so they self-mask (2^-144 flushes to 0).
__global__ __launch_bounds__(512) void attn(
    const u16* __restrict__ qk, const u16* __restrict__ vT,
    const u16* __restrict__ biasm, float* __restrict__ out) {
  const int bh = blockIdx.x;  // b*12+h
  const int qt = blockIdx.y;  // 0..4
  const int b = bh / 12, h = bh - b * 12;
  const int tid = threadIdx.x;
  const int lane = tid & 63;
  const int w = tid >> 6;     // 0..7
  const int quad = lane >> 4;
  const int l15 = lane & 15;

  const u16* qp = qk + (size_t)b * SEQ * 768 + h * 64;  // row stride 768
  const u16* kp = qp + (size_t)QKV_STRIDE;
  const u16* vtp = vT + (size_t)bh * 64 * VT_PITCH;
  const u16* bp = biasm + (size_t)h * SEQ * B_PITCH;

  __shared__ u16 Ks[64][72];     // [key][d]
  __shared__ u16 VTs[64][72];    // [d][key]
  __shared__ u16 Ps[8][16][72];  // per-wave P tile, XOR-swizzled chunks

  const int qrow0 = qt * 128 + w * 16;

  bf16x8 qf[2];
  {
    int row = qrow0 + l15;
    if (row > 576) row = 576;  // clamp; clamped rows never stored
    qf[0] = *(const bf16x8*)(qp + (size_t)row * 768 + quad * 8);
    qf[1] = *(const bf16x8*)(qp + (size_t)row * 768 + 32 + quad * 8);
  }
  int brow[4];
#pragma unroll
  for (int r = 0; r < 4; ++r) {
    int rr = qrow0 + quad * 4 + r;
    if (rr > 576) rr = 576;
    brow[r] = rr;
  }

  const short one_bf = (short)0x3F80;      // bf16 1.0
  const bf16x8 vones = {one_bf, one_bf, one_bf, one_bf,
                        one_bf, one_bf, one_bf, one_bf};

  f32x4 Ol = (f32x4){0.f, 0.f, 0.f, 0.f};  // row sums l (per quad-row)
  f32x4 O[4];
#pragma unroll
  for (int dt = 0; dt < 4; ++dt) O[dt] = (f32x4){0.f, 0.f, 0.f, 0.f};

  for (int kt = 0; kt < 10; ++kt) {
    const int kbase = kt * 64;
    // bias loads first (independent VMEM, latency overlaps staging)
    u16 bb[4][4];
#pragma unroll
    for (int nt = 0; nt < 4; ++nt)
#pragma unroll
      for (int r = 0; r < 4; ++r)
        bb[nt][r] = bp[(size_t)brow[r] * B_PITCH + kbase + nt * 16 + l15];

    // stage K [key][d] and V^T window [d][key] — 512 threads = one pass each
    {
      int rr = tid >> 3, ko = (tid & 7) << 3;
      int gk = kbase + rr;
      int4 kvv = make_int4(0, 0, 0, 0);
      if (gk < SEQ) kvv = *(const int4*)(kp + (size_t)gk * 768 + ko);
      *(int4*)&Ks[rr][ko] = kvv;
      *(int4*)&VTs[rr][ko] = *(const int4*)(vtp + (size_t)rr * VT_PITCH + kbase + ko);
    }
    __syncthreads();

    // S = Q K^T + bias  (bias as MFMA C-init; q pre-scaled by 0.125*log2e,
    // bias pre-scaled by log2e; pad keys: K=0, bias=-144 -> 2^s = 0)
    f32x4 s[4];
#pragma unroll
    for (int nt = 0; nt < 4; ++nt) {
      f32x4 z = (f32x4){bf2f(bb[nt][0]), bf2f(bb[nt][1]),
                        bf2f(bb[nt][2]), bf2f(bb[nt][3])};
      bf16x8 kf0 = *(const bf16x8*)(&Ks[nt * 16 + l15][quad * 8]);
      bf16x8 kf1 = *(const bf16x8*)(&Ks[nt * 16 + l15][32 + quad * 8]);
      z = __builtin_amdgcn_mfma_f32_16x16x32_bf16(qf[0], kf0, z, 0, 0, 0);
      z = __builtin_amdgcn_mfma_f32_16x16x32_bf16(qf[1], kf1, z, 0, 0, 0);
      s[nt] = z;
    }

    // p = exp2(s); truncate to bf16 into Ps (l comes from ones-MFMA below)
#pragma unroll
    for (int nt = 0; nt < 4; ++nt) {
#pragma unroll
      for (int r = 0; r < 4; ++r) {
        float p = exp2f(s[nt][r]);
        unsigned int u = __float_as_uint(p);
        Ps[w][quad * 4 + r][((nt ^ quad) << 4) + l15] = (u16)(u >> 16);
      }
    }

    // O += P V; Ol += P x ones (row-sum on the matrix pipe)
#pragma unroll
    for (int ks = 0; ks < 2; ++ks) {
      int cc = (ks * 32 + quad * 8) ^ ((l15 >> 2) << 4);
      bf16x8 pf = *(const bf16x8*)(&Ps[w][l15][cc]);
#pragma unroll
      for (int dt = 0; dt < 4; ++dt) {
        bf16x8 vf = *(const bf16x8*)(&VTs[dt * 16 + l15][ks * 32 + quad * 8]);
        O[dt] = __builtin_amdgcn_mfma_f32_16x16x32_bf16(pf, vf, O[dt], 0, 0, 0);
      }
      Ol = __builtin_amdgcn_mfma_f32_16x16x32_bf16(pf, vones, Ol, 0, 0, 0);
    }
    __syncthreads();  // protect Ks/VTs/Ps before next tile's staging
  }

  // epilogue: l available per-lane from the ones-MFMA (no reduction needed)
#pragma unroll
  for (int r = 0; r < 4; ++r) {
    int row = qrow0 + quad * 4 + r;
    if (row < SEQ) {
      float inv = 1.f / Ol[r];
#pragma unroll
      for (int dt = 0; dt < 4; ++dt)
        out[((size_t)(b * SEQ + row)) * 768 + h * 64 + dt * 16 + l15] = O[dt][r] * inv;
    }
  }
}

extern "C" void kernel_launch(void* const* d_in, const int* in_sizes, int n_in,
                              void* d_out, int out_size, void* d_ws, size_t ws_size,
                              hipStream_t stream) {
  const float* hs = (const float*)d_in[0];
  const float* Wq = (const float*)d_in[1];
  const float* bq = (const float*)d_in[2];
  const float* Wk = (const float*)d_in[3];
  const float* Wv = (const float*)d_in[4];
  const float* bv = (const float*)d_in[5];
  const float* table = (const float*)d_in[6];
  const int* idx = (const int*)d_in[7];
  float* out = (float*)d_out;

  char* ws = (char*)d_ws;
  u16* qkv = (u16*)ws;                          // [0, 42541056)
  u16* WT = (u16*)(ws + 42541056);              // phase 1
  u16* Xb = (u16*)(ws + 46080000);              // phase 1
  u16* vT = (u16*)(ws + 42541056);              // phase 2 (over WT + Xb head)
  u16* biasm = (u16*)(ws + 58269696);           // phase 2 (over Xb tail)

  // phase 1: prep (transpose_w + cvt_x) -> GEMM
  hipLaunchKernelGGL(prep, dim3(5190), dim3(256), 0, stream, Wq, Wk, Wv, hs, WT, Xb);
  hipLaunchKernelGGL(qkv_gemm, dim3(240), dim3(512), 0, stream, Xb, WT, bq, bv, qkv);
  // phase 2: prep2 (transpose_v + h-vectorized bias gather) -> attention
  hipLaunchKernelGGL(prep2, dim3(1537), dim3(256), 0, stream,
                     qkv + 2 * (size_t)QKV_STRIDE, vT, table, idx, biasm);
  hipLaunchKernelGGL(attn, dim3(192, 5), dim3(512), 0, stream, qkv, vT, biasm, out);
}